// Round 1
// baseline (28180.032 us; speedup 1.0000x reference)
//
#include <hip/hip_runtime.h>
#include <math.h>

#define NINP 64
#define NH 512
#define G4 2048   // 4*NH
#define T 64
#define BATCH 2048
#define LDIN 4097 // T*NINP+1

// GEMM tile
#define BM 64
#define BN 64
#define BK 16

__device__ __forceinline__ float sigmf(float x) { return 1.0f / (1.0f + expf(-x)); }

// C[m][n] = sum_pairs sum_k A[m*lda+k]*W[n*ldw+k] + bias0[n] + bias1[n] + pv[m]*pc[n*ldpc]
__global__ __launch_bounds__(256) void gates_gemm(
    const float* __restrict__ A0, int lda0, const float* __restrict__ W0, int ldw0, int K0,
    const float* __restrict__ A1, int lda1, const float* __restrict__ W1, int ldw1, int K1,
    const float* __restrict__ Ax, int ldax, const float* __restrict__ Wx, int ldwx, int Kx,
    const float* __restrict__ bias0, const float* __restrict__ bias1,
    const float* __restrict__ pv, const float* __restrict__ pc, int ldpc,
    float* __restrict__ C, int N)
{
    __shared__ float As[BM][BK + 1];
    __shared__ float Ws[BN][BK + 1];
    const int tid = threadIdx.x;
    const int m0 = blockIdx.y * BM;
    const int n0 = blockIdx.x * BN;
    const int tm = (tid & 15) * 4;
    const int tn = (tid >> 4) * 4;
    const int lk = tid & 15;   // k within tile
    const int lm = tid >> 4;   // row group
    float acc[4][4] = {};

    for (int p = 0; p < 3; ++p) {
        const float* A; const float* W; int lda, ldw, K;
        if (p == 0) { A = A0; W = W0; lda = lda0; ldw = ldw0; K = K0; }
        else if (p == 1) { A = A1; W = W1; lda = lda1; ldw = ldw1; K = K1; }
        else { A = Ax; W = Wx; lda = ldax; ldw = ldwx; K = Kx; }
        if (A == nullptr || K <= 0) continue;

        for (int k0 = 0; k0 < K; k0 += BK) {
            __syncthreads();
            #pragma unroll
            for (int i = 0; i < 4; ++i) {
                As[lm + i * 16][lk] = A[(size_t)(m0 + lm + i * 16) * lda + k0 + lk];
                Ws[lm + i * 16][lk] = W[(size_t)(n0 + lm + i * 16) * ldw + k0 + lk];
            }
            __syncthreads();
            #pragma unroll
            for (int k = 0; k < BK; ++k) {
                float a[4], w[4];
                #pragma unroll
                for (int i = 0; i < 4; ++i) a[i] = As[tm + i][k];
                #pragma unroll
                for (int j = 0; j < 4; ++j) w[j] = Ws[tn + j][k];
                #pragma unroll
                for (int i = 0; i < 4; ++i)
                    #pragma unroll
                    for (int j = 0; j < 4; ++j)
                        acc[i][j] = fmaf(a[i], w[j], acc[i][j]);
            }
        }
    }

    float bj[4], pcv[4];
    #pragma unroll
    for (int j = 0; j < 4; ++j) {
        int n = n0 + tn + j;
        float b = 0.f;
        if (bias0) b += bias0[n];
        if (bias1) b += bias1[n];
        bj[j] = b;
        pcv[j] = pc ? pc[(size_t)n * ldpc] : 0.f;
    }
    #pragma unroll
    for (int i = 0; i < 4; ++i) {
        int m = m0 + tm + i;
        float pvv = pv ? pv[m] : 0.f;
        #pragma unroll
        for (int j = 0; j < 4; ++j) {
            C[(size_t)m * N + n0 + tn + j] = acc[i][j] + bj[j] + pvv * pcv[j];
        }
    }
}

__global__ __launch_bounds__(256) void lstm_cell_k(const float* __restrict__ gates,
                                                   float* __restrict__ h, float* __restrict__ c)
{
    int idx = blockIdx.x * 256 + threadIdx.x;   // over BATCH*NH
    int b = idx >> 9;
    int j = idx & (NH - 1);
    const float* g = gates + (size_t)b * G4;
    float gi = g[j], gf = g[NH + j], gg = g[2 * NH + j], go = g[3 * NH + j];
    float cv = c[idx];
    float cn = sigmf(gf) * cv + sigmf(gi) * tanhf(gg);
    c[idx] = cn;
    h[idx] = sigmf(go) * tanhf(cn);
}

// one wave per batch row: dst[b*dstStride] = dot(h[b], Wl) + bl[0]
__global__ __launch_bounds__(256) void out_proj_k(const float* __restrict__ h,
                                                  const float* __restrict__ Wl,
                                                  const float* __restrict__ bl,
                                                  float* __restrict__ dst, int dstStride)
{
    int wave = threadIdx.x >> 6;
    int lane = threadIdx.x & 63;
    int b = blockIdx.x * 4 + wave;
    const float4* hv = (const float4*)(h + (size_t)b * NH);
    const float4* wv = (const float4*)Wl;
    float s = 0.f;
    #pragma unroll
    for (int r = 0; r < 2; ++r) {
        float4 a = hv[lane + r * 64];
        float4 w = wv[lane + r * 64];
        s += a.x * w.x + a.y * w.y + a.z * w.z + a.w * w.w;
    }
    #pragma unroll
    for (int off = 32; off > 0; off >>= 1) s += __shfl_down(s, off);
    if (lane == 0) dst[(size_t)b * dstStride] = s + bl[0];
}

__global__ __launch_bounds__(256) void pias_k(const float* __restrict__ outs_p,
                                              const float* __restrict__ input,
                                              float* __restrict__ pias,
                                              float* __restrict__ dout)
{
    int idx = blockIdx.x * 256 + threadIdx.x; // over T*BATCH
    int b = idx & (BATCH - 1);
    float scale = input[(size_t)b * LDIN + (LDIN - 1)];
    pias[idx] = fabsf(outs_p[idx]) * scale;
    if (idx < BATCH) dout[(size_t)idx * (T + 1) + T] = outs_p[(size_t)(T - 1) * BATCH + idx];
}

extern "C" void kernel_launch(void* const* d_in, const int* in_sizes, int n_in,
                              void* d_out, int out_size, void* d_ws, size_t ws_size,
                              hipStream_t stream)
{
    const float* input = (const float*)d_in[0];
    const float* Wih_p = (const float*)d_in[1];
    const float* Whh_p = (const float*)d_in[2];
    const float* bih_p = (const float*)d_in[3];
    const float* bhh_p = (const float*)d_in[4];
    const float* Wih1  = (const float*)d_in[5];
    const float* Whh1  = (const float*)d_in[6];
    const float* bih1  = (const float*)d_in[7];
    const float* bhh1  = (const float*)d_in[8];
    const float* Wih2  = (const float*)d_in[9];
    const float* Whh2  = (const float*)d_in[10];
    const float* bih2  = (const float*)d_in[11];
    const float* bhh2  = (const float*)d_in[12];
    const float* Wl    = (const float*)d_in[13];
    const float* bl    = (const float*)d_in[14];
    float* out = (float*)d_out;

    const size_t HC = (size_t)BATCH * NH; // 1M floats
    float* ws = (float*)d_ws;
    float* h_p = ws;
    float* c_p = ws + HC;
    float* h1  = ws + 2 * HC;
    float* c1  = ws + 3 * HC;
    float* h2  = ws + 4 * HC;
    float* c2  = ws + 5 * HC;
    float* gates  = ws + 6 * HC;                       // BATCH*G4 = 4M floats
    float* outs_p = ws + 6 * HC + (size_t)BATCH * G4;  // T*BATCH
    float* pias   = outs_p + (size_t)T * BATCH;        // T*BATCH

    hipMemsetAsync(ws, 0, 6 * HC * sizeof(float), stream);

    dim3 ggrid(G4 / BN, BATCH / BM);
    dim3 gblk(256);
    dim3 cgrid((BATCH * NH) / 256);
    dim3 ogrid(BATCH / 4);

    // Phase 1: LSTM_p over T steps
    for (int t = 0; t < T; ++t) {
        gates_gemm<<<ggrid, gblk, 0, stream>>>(
            h_p, NH, Whh_p, NH, NH,
            nullptr, 0, nullptr, 0, 0,
            input + (size_t)t * NINP, LDIN, Wih_p, NINP, NINP,
            bih_p, bhh_p, nullptr, nullptr, 0,
            gates, G4);
        lstm_cell_k<<<cgrid, 256, 0, stream>>>(gates, h_p, c_p);
        out_proj_k<<<ogrid, 256, 0, stream>>>(h_p, Wl, bl, outs_p + (size_t)t * BATCH, 1);
    }

    pias_k<<<(T * BATCH) / 256, 256, 0, stream>>>(outs_p, input, pias, out);

    // Phase 2: 2-layer stacked LSTM over T steps
    for (int t = 0; t < T; ++t) {
        gates_gemm<<<ggrid, gblk, 0, stream>>>(
            h1, NH, Whh1, NH, NH,
            nullptr, 0, nullptr, 0, 0,
            input + (size_t)t * NINP, LDIN, Wih1, NINP + 1, NINP,
            bih1, bhh1, pias + (size_t)t * BATCH, Wih1 + NINP, NINP + 1,
            gates, G4);
        lstm_cell_k<<<cgrid, 256, 0, stream>>>(gates, h1, c1);
        gates_gemm<<<ggrid, gblk, 0, stream>>>(
            h1, NH, Wih2, NH, NH,
            h2, NH, Whh2, NH, NH,
            nullptr, 0, nullptr, 0, 0,
            bih2, bhh2, nullptr, nullptr, 0,
            gates, G4);
        lstm_cell_k<<<cgrid, 256, 0, stream>>>(gates, h2, c2);
        out_proj_k<<<ogrid, 256, 0, stream>>>(h2, Wl, bl, out + t, T + 1);
    }
}

// Round 2
// 9870.988 us; speedup vs baseline: 2.8548x; 2.8548x over previous
//
#include <hip/hip_runtime.h>
#include <math.h>

#define NINP 64
#define NH 512
#define G4 2048   // 4*NH
#define T 64
#define BATCH 2048
#define LDIN 4097 // T*NINP+1

typedef __bf16 bf16x8 __attribute__((ext_vector_type(8)));
typedef float f32x4 __attribute__((ext_vector_type(4)));
typedef unsigned short ushort8 __attribute__((ext_vector_type(8)));

__device__ __forceinline__ float sigmf(float x) { return 1.0f / (1.0f + expf(-x)); }

// bf16 RNE split helpers (bit tricks, no header dependency)
__device__ __forceinline__ unsigned int bfhi_bits(float f) {
    unsigned int u = __float_as_uint(f);
    return (u + 0x7fffu + ((u >> 16) & 1u)) >> 16;
}
__device__ __forceinline__ float bf_to_f(unsigned int bits) {
    return __uint_as_float(bits << 16);
}

// ---------------------------------------------------------------------------
// Fused gates-GEMM (split-bf16 MFMA) + LSTM cell epilogue.
// Gate columns are PERMUTED: n' = j*4 + g  (orig n = g*512 + j), so lanes
// {4k..4k+3} of a wave hold gates i,f,g,o of the same (b, j).
// Tile: 128 (batch) x 64 (n'), BK=32, 4 waves (2m x 2n), wave tile 64x32.
// ---------------------------------------------------------------------------
__global__ __launch_bounds__(256) void lstm_step_k(
    const ushort* __restrict__ A0hi, const ushort* __restrict__ A0lo, int lda0,
    const ushort* __restrict__ W0hi, const ushort* __restrict__ W0lo, int K0,
    const ushort* __restrict__ A1hi, const ushort* __restrict__ A1lo, int lda1,
    const ushort* __restrict__ W1hi, const ushort* __restrict__ W1lo, int K1,
    const float*  __restrict__ Xf, int ldx,
    const ushort* __restrict__ Wxhi, const ushort* __restrict__ Wxlo, int Kx,
    const float* __restrict__ biasperm,
    const float* __restrict__ pv, const float* __restrict__ pcperm,
    float* __restrict__ c, float* __restrict__ hf32,
    ushort* __restrict__ hhi, ushort* __restrict__ hlo)
{
    __shared__ ushort As_hi[128][40];
    __shared__ ushort As_lo[128][40];
    __shared__ ushort Ws_hi[64][40];
    __shared__ ushort Ws_lo[64][40];

    const int tid = threadIdx.x;
    const int lane = tid & 63;
    const int wid = tid >> 6;
    const int wm = wid >> 1;      // 0..1 (m half)
    const int wn = wid & 1;       // 0..1 (n half)
    const int fr = lane & 15;     // row within fragment
    const int fg = lane >> 4;     // k-group (0..3) -> k offset fg*8
    const int m0 = blockIdx.y * 128;
    const int n0 = blockIdx.x * 64;
    const int srow = tid >> 2;          // 0..63
    const int scol = (tid & 3) * 8;     // 0,8,16,24

    f32x4 acc[4][2] = {};

    for (int p = 0; p < 3; ++p) {
        const ushort *Ahi, *Alo, *Whi, *Wlo;
        const float* Xp = nullptr;
        int lda_, Kp;
        if (p == 0) { Ahi = A0hi; Alo = A0lo; lda_ = lda0; Whi = W0hi; Wlo = W0lo; Kp = K0; }
        else if (p == 1) { Ahi = A1hi; Alo = A1lo; lda_ = lda1; Whi = W1hi; Wlo = W1lo; Kp = K1; }
        else { Ahi = nullptr; Alo = nullptr; lda_ = ldx; Whi = Wxhi; Wlo = Wxlo; Kp = Kx; Xp = Xf; }
        if (Kp <= 0) continue;
        if (p < 2 && Ahi == nullptr) continue;
        if (p == 2 && Xp == nullptr) continue;

        for (int kt = 0; kt < Kp; kt += 32) {
            __syncthreads();
            if (Xp == nullptr) {
                #pragma unroll
                for (int rr = 0; rr < 2; ++rr) {
                    int row = srow + rr * 64;
                    *(ushort8*)&As_hi[row][scol] =
                        *(const ushort8*)&Ahi[(size_t)(m0 + row) * lda_ + kt + scol];
                    *(ushort8*)&As_lo[row][scol] =
                        *(const ushort8*)&Alo[(size_t)(m0 + row) * lda_ + kt + scol];
                }
            } else {
                #pragma unroll
                for (int rr = 0; rr < 2; ++rr) {
                    int row = srow + rr * 64;
                    const float* src = Xp + (size_t)(m0 + row) * lda_ + kt + scol;
                    ushort8 hv, lv;
                    #pragma unroll
                    for (int e = 0; e < 8; ++e) {
                        float v = src[e];
                        unsigned int hb = bfhi_bits(v);
                        hv[e] = (unsigned short)hb;
                        lv[e] = (unsigned short)bfhi_bits(v - bf_to_f(hb));
                    }
                    *(ushort8*)&As_hi[row][scol] = hv;
                    *(ushort8*)&As_lo[row][scol] = lv;
                }
            }
            *(ushort8*)&Ws_hi[srow][scol] =
                *(const ushort8*)&Whi[(size_t)(n0 + srow) * Kp + kt + scol];
            *(ushort8*)&Ws_lo[srow][scol] =
                *(const ushort8*)&Wlo[(size_t)(n0 + srow) * Kp + kt + scol];
            __syncthreads();

            bf16x8 ah[4], al[4], wh[2], wl[2];
            #pragma unroll
            for (int im = 0; im < 4; ++im)
                ah[im] = *(const bf16x8*)&As_hi[wm * 64 + im * 16 + fr][fg * 8];
            #pragma unroll
            for (int in = 0; in < 2; ++in)
                wh[in] = *(const bf16x8*)&Ws_hi[wn * 32 + in * 16 + fr][fg * 8];
            #pragma unroll
            for (int im = 0; im < 4; ++im)
                #pragma unroll
                for (int in = 0; in < 2; ++in)
                    acc[im][in] = __builtin_amdgcn_mfma_f32_16x16x32_bf16(ah[im], wh[in], acc[im][in], 0, 0, 0);
            #pragma unroll
            for (int in = 0; in < 2; ++in)
                wl[in] = *(const bf16x8*)&Ws_lo[wn * 32 + in * 16 + fr][fg * 8];
            #pragma unroll
            for (int im = 0; im < 4; ++im)
                #pragma unroll
                for (int in = 0; in < 2; ++in)
                    acc[im][in] = __builtin_amdgcn_mfma_f32_16x16x32_bf16(ah[im], wl[in], acc[im][in], 0, 0, 0);
            #pragma unroll
            for (int im = 0; im < 4; ++im)
                al[im] = *(const bf16x8*)&As_lo[wm * 64 + im * 16 + fr][fg * 8];
            #pragma unroll
            for (int im = 0; im < 4; ++im)
                #pragma unroll
                for (int in = 0; in < 2; ++in)
                    acc[im][in] = __builtin_amdgcn_mfma_f32_16x16x32_bf16(al[im], wh[in], acc[im][in], 0, 0, 0);
        }
    }

    // Epilogue: bias + pia term, 4-lane gate exchange, cell update, h/c writes.
    #pragma unroll
    for (int im = 0; im < 4; ++im) {
        int rowb = m0 + wm * 64 + im * 16 + fg * 4;
        #pragma unroll
        for (int in = 0; in < 2; ++in) {
            int np = n0 + wn * 32 + in * 16 + fr;
            float bias = biasperm[np];
            float pcv = (pcperm != nullptr) ? pcperm[np] : 0.0f;
            int j = np >> 2;
            #pragma unroll
            for (int r = 0; r < 4; ++r) {
                int b = rowb + r;
                float g = acc[im][in][r] + bias;
                if (pv != nullptr) g += pv[b] * pcv;
                int bl = lane & ~3;
                float gi = __shfl(g, bl + 0);
                float gf = __shfl(g, bl + 1);
                float gt = __shfl(g, bl + 2);
                float go = __shfl(g, bl + 3);
                if ((lane & 3) == 0) {
                    size_t idx = (size_t)b * NH + j;
                    float cold = c[idx];
                    float cn = sigmf(gf) * cold + sigmf(gi) * tanhf(gt);
                    float hn = sigmf(go) * tanhf(cn);
                    c[idx] = cn;
                    hf32[idx] = hn;
                    unsigned int hb = bfhi_bits(hn);
                    hhi[idx] = (unsigned short)hb;
                    hlo[idx] = (unsigned short)bfhi_bits(hn - bf_to_f(hb));
                }
            }
        }
    }
}

// one wave per batch row: dst[b*dstStride] = dot(h[b], Wl) + bl[0]
__global__ __launch_bounds__(256) void out_proj_k(const float* __restrict__ h,
                                                  const float* __restrict__ Wl,
                                                  const float* __restrict__ bl,
                                                  float* __restrict__ dst, int dstStride)
{
    int wave = threadIdx.x >> 6;
    int lane = threadIdx.x & 63;
    int b = blockIdx.x * 4 + wave;
    const float4* hv = (const float4*)(h + (size_t)b * NH);
    const float4* wv = (const float4*)Wl;
    float s = 0.f;
    #pragma unroll
    for (int r = 0; r < 2; ++r) {
        float4 a = hv[lane + r * 64];
        float4 w = wv[lane + r * 64];
        s += a.x * w.x + a.y * w.y + a.z * w.z + a.w * w.w;
    }
    #pragma unroll
    for (int off = 32; off > 0; off >>= 1) s += __shfl_down(s, off);
    if (lane == 0) dst[(size_t)b * dstStride] = s + bl[0];
}

__global__ __launch_bounds__(256) void pias_k(const float* __restrict__ outs_p,
                                              const float* __restrict__ input,
                                              float* __restrict__ pias,
                                              float* __restrict__ dout)
{
    int idx = blockIdx.x * 256 + threadIdx.x; // over T*BATCH
    int b = idx & (BATCH - 1);
    float scale = input[(size_t)b * LDIN + (LDIN - 1)];
    pias[idx] = fabsf(outs_p[idx]) * scale;
    if (idx < BATCH) dout[(size_t)idx * (T + 1) + T] = outs_p[(size_t)(T - 1) * BATCH + idx];
}

// Split W[4NH][ldw] (cols 0..K-1) into permuted bf16 hi/lo, n' = j*4+g.
__global__ __launch_bounds__(256) void split_perm_w_k(const float* __restrict__ W,
                                                      ushort* __restrict__ whi,
                                                      ushort* __restrict__ wlo,
                                                      int ldw, int kshift)
{
    int idx = blockIdx.x * 256 + threadIdx.x;
    int K = 1 << kshift;
    int np = idx >> kshift;
    int k = idx & (K - 1);
    int orig = ((np & 3) << 9) | (np >> 2);
    float v = W[(size_t)orig * ldw + k];
    unsigned int hb = bfhi_bits(v);
    whi[idx] = (unsigned short)hb;
    wlo[idx] = (unsigned short)bfhi_bits(v - bf_to_f(hb));
}

__global__ __launch_bounds__(256) void bias_prep_k(const float* __restrict__ bih,
                                                   const float* __restrict__ bhh,
                                                   float* __restrict__ bperm)
{
    int np = blockIdx.x * 256 + threadIdx.x;
    int orig = ((np & 3) << 9) | (np >> 2);
    bperm[np] = bih[orig] + bhh[orig];
}

__global__ __launch_bounds__(256) void pc_prep_k(const float* __restrict__ Wih1,
                                                 float* __restrict__ pc)
{
    int np = blockIdx.x * 256 + threadIdx.x;
    int orig = ((np & 3) << 9) | (np >> 2);
    pc[np] = Wih1[(size_t)orig * (NINP + 1) + NINP];
}

extern "C" void kernel_launch(void* const* d_in, const int* in_sizes, int n_in,
                              void* d_out, int out_size, void* d_ws, size_t ws_size,
                              hipStream_t stream)
{
    const float* input = (const float*)d_in[0];
    const float* Wih_p = (const float*)d_in[1];
    const float* Whh_p = (const float*)d_in[2];
    const float* bih_p = (const float*)d_in[3];
    const float* bhh_p = (const float*)d_in[4];
    const float* Wih1  = (const float*)d_in[5];
    const float* Whh1  = (const float*)d_in[6];
    const float* bih1  = (const float*)d_in[7];
    const float* bhh1  = (const float*)d_in[8];
    const float* Wih2  = (const float*)d_in[9];
    const float* Whh2  = (const float*)d_in[10];
    const float* bih2  = (const float*)d_in[11];
    const float* bhh2  = (const float*)d_in[12];
    const float* Wl    = (const float*)d_in[13];
    const float* bl    = (const float*)d_in[14];
    float* out = (float*)d_out;

    const size_t HC = (size_t)BATCH * NH;       // 1M elems
    char* p = (char*)d_ws;
    auto alloc = [&](size_t bytes) { char* r = p; p += (bytes + 255) & ~(size_t)255; return r; };

    // --- zeroed region first ---
    float* c_p = (float*)alloc(HC * 4);
    float* c1  = (float*)alloc(HC * 4);
    float* c2  = (float*)alloc(HC * 4);
    float* h_p = (float*)alloc(HC * 4);
    float* h1  = (float*)alloc(HC * 4);
    float* h2  = (float*)alloc(HC * 4);
    ushort* hps_hi[2]; ushort* hps_lo[2];
    ushort* h1s_hi[2]; ushort* h1s_lo[2];
    ushort* h2s_hi[2]; ushort* h2s_lo[2];
    for (int i = 0; i < 2; ++i) { hps_hi[i] = (ushort*)alloc(HC * 2); hps_lo[i] = (ushort*)alloc(HC * 2); }
    for (int i = 0; i < 2; ++i) { h1s_hi[i] = (ushort*)alloc(HC * 2); h1s_lo[i] = (ushort*)alloc(HC * 2); }
    for (int i = 0; i < 2; ++i) { h2s_hi[i] = (ushort*)alloc(HC * 2); h2s_lo[i] = (ushort*)alloc(HC * 2); }
    size_t zbytes = (size_t)(p - (char*)d_ws);

    // --- non-zeroed ---
    float* outs_p = (float*)alloc((size_t)T * BATCH * 4);
    float* pias   = (float*)alloc((size_t)T * BATCH * 4);
    ushort* WhhP_hi = (ushort*)alloc((size_t)G4 * NH * 2);
    ushort* WhhP_lo = (ushort*)alloc((size_t)G4 * NH * 2);
    ushort* WihP_hi = (ushort*)alloc((size_t)G4 * NINP * 2);
    ushort* WihP_lo = (ushort*)alloc((size_t)G4 * NINP * 2);
    ushort* Whh1_hi = (ushort*)alloc((size_t)G4 * NH * 2);
    ushort* Whh1_lo = (ushort*)alloc((size_t)G4 * NH * 2);
    ushort* Wih1x_hi = (ushort*)alloc((size_t)G4 * NINP * 2);
    ushort* Wih1x_lo = (ushort*)alloc((size_t)G4 * NINP * 2);
    ushort* Wih2_hi = (ushort*)alloc((size_t)G4 * NH * 2);
    ushort* Wih2_lo = (ushort*)alloc((size_t)G4 * NH * 2);
    ushort* Whh2_hi = (ushort*)alloc((size_t)G4 * NH * 2);
    ushort* Whh2_lo = (ushort*)alloc((size_t)G4 * NH * 2);
    float* biasP = (float*)alloc(G4 * 4);
    float* bias1 = (float*)alloc(G4 * 4);
    float* bias2 = (float*)alloc(G4 * 4);
    float* pc1   = (float*)alloc(G4 * 4);

    hipMemsetAsync(d_ws, 0, zbytes, stream);

    // weight prep
    split_perm_w_k<<<(G4 * NH) / 256, 256, 0, stream>>>(Whh_p, WhhP_hi, WhhP_lo, NH, 9);
    split_perm_w_k<<<(G4 * NINP) / 256, 256, 0, stream>>>(Wih_p, WihP_hi, WihP_lo, NINP, 6);
    split_perm_w_k<<<(G4 * NH) / 256, 256, 0, stream>>>(Whh1, Whh1_hi, Whh1_lo, NH, 9);
    split_perm_w_k<<<(G4 * NINP) / 256, 256, 0, stream>>>(Wih1, Wih1x_hi, Wih1x_lo, NINP + 1, 6);
    split_perm_w_k<<<(G4 * NH) / 256, 256, 0, stream>>>(Wih2, Wih2_hi, Wih2_lo, NH, 9);
    split_perm_w_k<<<(G4 * NH) / 256, 256, 0, stream>>>(Whh2, Whh2_hi, Whh2_lo, NH, 9);
    bias_prep_k<<<G4 / 256, 256, 0, stream>>>(bih_p, bhh_p, biasP);
    bias_prep_k<<<G4 / 256, 256, 0, stream>>>(bih1, bhh1, bias1);
    bias_prep_k<<<G4 / 256, 256, 0, stream>>>(bih2, bhh2, bias2);
    pc_prep_k<<<G4 / 256, 256, 0, stream>>>(Wih1, pc1);

    dim3 sgrid(G4 / 64, BATCH / 128);
    dim3 ogrid(BATCH / 4);

    // Phase 1
    for (int t = 0; t < T; ++t) {
        int rb = t & 1, wb = (t + 1) & 1;
        lstm_step_k<<<sgrid, 256, 0, stream>>>(
            hps_hi[rb], hps_lo[rb], NH, WhhP_hi, WhhP_lo, NH,
            nullptr, nullptr, 0, nullptr, nullptr, 0,
            input + (size_t)t * NINP, LDIN, WihP_hi, WihP_lo, NINP,
            biasP, nullptr, nullptr,
            c_p, h_p, hps_hi[wb], hps_lo[wb]);
        out_proj_k<<<ogrid, 256, 0, stream>>>(h_p, Wl, bl, outs_p + (size_t)t * BATCH, 1);
    }

    pias_k<<<(T * BATCH) / 256, 256, 0, stream>>>(outs_p, input, pias, out);

    // Phase 2
    for (int t = 0; t < T; ++t) {
        int rb = t & 1, wb = (t + 1) & 1;
        lstm_step_k<<<sgrid, 256, 0, stream>>>(
            h1s_hi[rb], h1s_lo[rb], NH, Whh1_hi, Whh1_lo, NH,
            nullptr, nullptr, 0, nullptr, nullptr, 0,
            input + (size_t)t * NINP, LDIN, Wih1x_hi, Wih1x_lo, NINP,
            bias1, pias + (size_t)t * BATCH, pc1,
            c1, h1, h1s_hi[wb], h1s_lo[wb]);
        lstm_step_k<<<sgrid, 256, 0, stream>>>(
            h1s_hi[wb], h1s_lo[wb], NH, Wih2_hi, Wih2_lo, NH,
            h2s_hi[rb], h2s_lo[rb], NH, Whh2_hi, Whh2_lo, NH,
            nullptr, 0, nullptr, nullptr, 0,
            bias2, nullptr, nullptr,
            c2, h2, h2s_hi[wb], h2s_lo[wb]);
        out_proj_k<<<ogrid, 256, 0, stream>>>(h2, Wl, bl, out + t, T + 1);
    }
}

// Round 3
// 7062.403 us; speedup vs baseline: 3.9901x; 1.3977x over previous
//
#include <hip/hip_runtime.h>
#include <math.h>

#define NINP 64
#define NH 512
#define G4 2048   // 4*NH
#define T 64
#define BATCH 2048
#define LDIN 4097 // T*NINP+1

typedef __bf16 bf16x8 __attribute__((ext_vector_type(8)));
typedef float f32x4 __attribute__((ext_vector_type(4)));
typedef unsigned short ushort8 __attribute__((ext_vector_type(8)));

__device__ __forceinline__ float sigmf(float x) { return 1.0f / (1.0f + expf(-x)); }

__device__ __forceinline__ unsigned int bfhi_bits(float f) {
    unsigned int u = __float_as_uint(f);
    return (u + 0x7fffu + ((u >> 16) & 1u)) >> 16;
}
__device__ __forceinline__ float bf_to_f(unsigned int bits) {
    return __uint_as_float(bits << 16);
}

// ---------------------------------------------------------------------------
// Fused gates-GEMM (split-bf16 MFMA) + LSTM cell epilogue (LDS re-layout).
// Gate columns PERMUTED: n' = j*4 + g. Tile: 128(b) x 64(n'), BK=32, 4 waves.
// Optional prologue: out-projection of previous step's h (1 row per wave).
// ---------------------------------------------------------------------------
__global__ __launch_bounds__(256) void lstm_step_k(
    const ushort* __restrict__ A0hi, const ushort* __restrict__ A0lo, int lda0,
    const ushort* __restrict__ W0hi, const ushort* __restrict__ W0lo, int K0,
    const ushort* __restrict__ A1hi, const ushort* __restrict__ A1lo, int lda1,
    const ushort* __restrict__ W1hi, const ushort* __restrict__ W1lo, int K1,
    const float*  __restrict__ Xf, int ldx,
    const ushort* __restrict__ Wxhi, const ushort* __restrict__ Wxlo, int Kx,
    const float* __restrict__ biasperm,
    const float* __restrict__ pv, const float* __restrict__ pcperm,
    float* __restrict__ c,
    ushort* __restrict__ hhi, ushort* __restrict__ hlo,
    const ushort* __restrict__ ophi, const ushort* __restrict__ oplo,
    const float* __restrict__ Wl, const float* __restrict__ blv,
    float* __restrict__ odst, int ostride)
{
    // LDS: staging buffers aliased with the f32 gate re-layout buffer.
    __shared__ float smemf[128 * 66];              // 33792 B
    float (*Gs)[66] = (float(*)[66])smemf;
    ushort* sm = (ushort*)smemf;
    ushort (*As_hi)[40] = (ushort(*)[40])(sm);            // 128*40
    ushort (*As_lo)[40] = (ushort(*)[40])(sm + 5120);     // 128*40
    ushort (*Ws_hi)[40] = (ushort(*)[40])(sm + 10240);    // 64*40
    ushort (*Ws_lo)[40] = (ushort(*)[40])(sm + 12800);    // 64*40

    const int tid = threadIdx.x;
    const int lane = tid & 63;
    const int wid = tid >> 6;

    // ---- prologue: out-projection of previous h (before any barrier) ----
    if (ophi != nullptr) {
        int bid = blockIdx.y * gridDim.x + blockIdx.x;
        int row = bid * 4 + wid;
        ushort8 hh8 = *(const ushort8*)&ophi[(size_t)row * NH + lane * 8];
        ushort8 hl8 = *(const ushort8*)&oplo[(size_t)row * NH + lane * 8];
        const float4* wv = (const float4*)(Wl + lane * 8);
        float4 w0 = wv[0], w1 = wv[1];
        float wreg[8] = {w0.x, w0.y, w0.z, w0.w, w1.x, w1.y, w1.z, w1.w};
        float s = 0.f;
        #pragma unroll
        for (int e = 0; e < 8; ++e) {
            float h = bf_to_f(hh8[e]) + bf_to_f(hl8[e]);
            s = fmaf(h, wreg[e], s);
        }
        #pragma unroll
        for (int off = 32; off > 0; off >>= 1) s += __shfl_down(s, off);
        if (lane == 0) odst[(size_t)row * ostride] = s + blv[0];
    }

    const int wm = wid >> 1;
    const int wn = wid & 1;
    const int fr = lane & 15;
    const int fg = lane >> 4;
    const int m0 = blockIdx.y * 128;
    const int n0 = blockIdx.x * 64;
    const int srow = tid >> 2;
    const int scol = (tid & 3) * 8;

    f32x4 acc[4][2] = {};

    for (int p = 0; p < 3; ++p) {
        const ushort *Ahi, *Alo, *Whi, *Wlo;
        const float* Xp = nullptr;
        int lda_, Kp;
        if (p == 0) { Ahi = A0hi; Alo = A0lo; lda_ = lda0; Whi = W0hi; Wlo = W0lo; Kp = K0; }
        else if (p == 1) { Ahi = A1hi; Alo = A1lo; lda_ = lda1; Whi = W1hi; Wlo = W1lo; Kp = K1; }
        else { Ahi = nullptr; Alo = nullptr; lda_ = ldx; Whi = Wxhi; Wlo = Wxlo; Kp = Kx; Xp = Xf; }
        if (Kp <= 0) continue;
        if (p < 2 && Ahi == nullptr) continue;
        if (p == 2 && Xp == nullptr) continue;

        for (int kt = 0; kt < Kp; kt += 32) {
            __syncthreads();
            if (Xp == nullptr) {
                #pragma unroll
                for (int rr = 0; rr < 2; ++rr) {
                    int row = srow + rr * 64;
                    *(ushort8*)&As_hi[row][scol] =
                        *(const ushort8*)&Ahi[(size_t)(m0 + row) * lda_ + kt + scol];
                    *(ushort8*)&As_lo[row][scol] =
                        *(const ushort8*)&Alo[(size_t)(m0 + row) * lda_ + kt + scol];
                }
            } else {
                #pragma unroll
                for (int rr = 0; rr < 2; ++rr) {
                    int row = srow + rr * 64;
                    const float* src = Xp + (size_t)(m0 + row) * lda_ + kt + scol;
                    ushort8 hv, lv;
                    #pragma unroll
                    for (int e = 0; e < 8; ++e) {
                        float v = src[e];
                        unsigned int hb = bfhi_bits(v);
                        hv[e] = (unsigned short)hb;
                        lv[e] = (unsigned short)bfhi_bits(v - bf_to_f(hb));
                    }
                    *(ushort8*)&As_hi[row][scol] = hv;
                    *(ushort8*)&As_lo[row][scol] = lv;
                }
            }
            *(ushort8*)&Ws_hi[srow][scol] =
                *(const ushort8*)&Whi[(size_t)(n0 + srow) * Kp + kt + scol];
            *(ushort8*)&Ws_lo[srow][scol] =
                *(const ushort8*)&Wlo[(size_t)(n0 + srow) * Kp + kt + scol];
            __syncthreads();

            bf16x8 ah[4], al[4], wh[2], wl[2];
            #pragma unroll
            for (int im = 0; im < 4; ++im)
                ah[im] = *(const bf16x8*)&As_hi[wm * 64 + im * 16 + fr][fg * 8];
            #pragma unroll
            for (int in = 0; in < 2; ++in)
                wh[in] = *(const bf16x8*)&Ws_hi[wn * 32 + in * 16 + fr][fg * 8];
            #pragma unroll
            for (int im = 0; im < 4; ++im)
                #pragma unroll
                for (int in = 0; in < 2; ++in)
                    acc[im][in] = __builtin_amdgcn_mfma_f32_16x16x32_bf16(ah[im], wh[in], acc[im][in], 0, 0, 0);
            #pragma unroll
            for (int in = 0; in < 2; ++in)
                wl[in] = *(const bf16x8*)&Ws_lo[wn * 32 + in * 16 + fr][fg * 8];
            #pragma unroll
            for (int im = 0; im < 4; ++im)
                #pragma unroll
                for (int in = 0; in < 2; ++in)
                    acc[im][in] = __builtin_amdgcn_mfma_f32_16x16x32_bf16(ah[im], wl[in], acc[im][in], 0, 0, 0);
            #pragma unroll
            for (int im = 0; im < 4; ++im)
                al[im] = *(const bf16x8*)&As_lo[wm * 64 + im * 16 + fr][fg * 8];
            #pragma unroll
            for (int im = 0; im < 4; ++im)
                #pragma unroll
                for (int in = 0; in < 2; ++in)
                    acc[im][in] = __builtin_amdgcn_mfma_f32_16x16x32_bf16(al[im], wh[in], acc[im][in], 0, 0, 0);
        }
    }

    // ---- epilogue stage 1: bias + pia, dump fragments to LDS (f32) ----
    __syncthreads();   // all waves done reading As/Ws (aliased with Gs)
    #pragma unroll
    for (int im = 0; im < 4; ++im) {
        int rowl = wm * 64 + im * 16 + fg * 4;
        #pragma unroll
        for (int in = 0; in < 2; ++in) {
            int npl = wn * 32 + in * 16 + fr;
            int np = n0 + npl;
            float bias = biasperm[np];
            float pcv = (pcperm != nullptr) ? pcperm[np] : 0.0f;
            #pragma unroll
            for (int r = 0; r < 4; ++r) {
                float g = acc[im][in][r] + bias;
                if (pv != nullptr) g += pv[m0 + rowl + r] * pcv;
                Gs[rowl + r][npl] = g;
            }
        }
    }
    __syncthreads();

    // ---- epilogue stage 2: per-cell update, fully coalesced I/O ----
    {
        int bloc = tid >> 1;
        int j8 = (tid & 1) * 8;
        int bglob = m0 + bloc;
        int jbase = (n0 >> 2) + j8;
        size_t idx = (size_t)bglob * NH + jbase;
        float4 cold0 = *(const float4*)&c[idx];
        float4 cold1 = *(const float4*)&c[idx + 4];
        float cold[8] = {cold0.x, cold0.y, cold0.z, cold0.w,
                         cold1.x, cold1.y, cold1.z, cold1.w};
        float cn[8], hn[8];
        #pragma unroll
        for (int jj = 0; jj < 8; ++jj) {
            int col = (j8 + jj) * 4;
            float2 gab = *(const float2*)&Gs[bloc][col];
            float2 gcd = *(const float2*)&Gs[bloc][col + 2];
            float cnv = sigmf(gab.y) * cold[jj] + sigmf(gab.x) * tanhf(gcd.x);
            cn[jj] = cnv;
            hn[jj] = sigmf(gcd.y) * tanhf(cnv);
        }
        float4 cs0 = {cn[0], cn[1], cn[2], cn[3]};
        float4 cs1 = {cn[4], cn[5], cn[6], cn[7]};
        *(float4*)&c[idx] = cs0;
        *(float4*)&c[idx + 4] = cs1;
        ushort8 hh, hl;
        #pragma unroll
        for (int jj = 0; jj < 8; ++jj) {
            unsigned int hb = bfhi_bits(hn[jj]);
            hh[jj] = (unsigned short)hb;
            hl[jj] = (unsigned short)bfhi_bits(hn[jj] - bf_to_f(hb));
        }
        *(ushort8*)&hhi[idx] = hh;
        *(ushort8*)&hlo[idx] = hl;
    }
}

// Standalone out-projection from hi/lo split h (tail steps).
__global__ __launch_bounds__(256) void out_proj_hl(const ushort* __restrict__ hhi,
                                                   const ushort* __restrict__ hlo,
                                                   const float* __restrict__ Wl,
                                                   const float* __restrict__ blv,
                                                   float* __restrict__ dst, int dstStride)
{
    int wave = threadIdx.x >> 6;
    int lane = threadIdx.x & 63;
    int row = blockIdx.x * 4 + wave;
    ushort8 hh8 = *(const ushort8*)&hhi[(size_t)row * NH + lane * 8];
    ushort8 hl8 = *(const ushort8*)&hlo[(size_t)row * NH + lane * 8];
    const float4* wv = (const float4*)(Wl + lane * 8);
    float4 w0 = wv[0], w1 = wv[1];
    float wreg[8] = {w0.x, w0.y, w0.z, w0.w, w1.x, w1.y, w1.z, w1.w};
    float s = 0.f;
    #pragma unroll
    for (int e = 0; e < 8; ++e) {
        float h = bf_to_f(hh8[e]) + bf_to_f(hl8[e]);
        s = fmaf(h, wreg[e], s);
    }
    #pragma unroll
    for (int off = 32; off > 0; off >>= 1) s += __shfl_down(s, off);
    if (lane == 0) dst[(size_t)row * dstStride] = s + blv[0];
}

__global__ __launch_bounds__(256) void pias_k(const float* __restrict__ outs_p,
                                              const float* __restrict__ input,
                                              float* __restrict__ pias,
                                              float* __restrict__ dout)
{
    int idx = blockIdx.x * 256 + threadIdx.x; // over T*BATCH
    int b = idx & (BATCH - 1);
    float scale = input[(size_t)b * LDIN + (LDIN - 1)];
    pias[idx] = fabsf(outs_p[idx]) * scale;
    if (idx < BATCH) dout[(size_t)idx * (T + 1) + T] = outs_p[(size_t)(T - 1) * BATCH + idx];
}

// Split W[4NH][ldw] (cols 0..K-1) into permuted bf16 hi/lo, n' = j*4+g.
__global__ __launch_bounds__(256) void split_perm_w_k(const float* __restrict__ W,
                                                      ushort* __restrict__ whi,
                                                      ushort* __restrict__ wlo,
                                                      int ldw, int kshift)
{
    int idx = blockIdx.x * 256 + threadIdx.x;
    int K = 1 << kshift;
    int np = idx >> kshift;
    int k = idx & (K - 1);
    int orig = ((np & 3) << 9) | (np >> 2);
    float v = W[(size_t)orig * ldw + k];
    unsigned int hb = bfhi_bits(v);
    whi[idx] = (unsigned short)hb;
    wlo[idx] = (unsigned short)bfhi_bits(v - bf_to_f(hb));
}

__global__ __launch_bounds__(256) void bias_prep_k(const float* __restrict__ bih,
                                                   const float* __restrict__ bhh,
                                                   float* __restrict__ bperm)
{
    int np = blockIdx.x * 256 + threadIdx.x;
    int orig = ((np & 3) << 9) | (np >> 2);
    bperm[np] = bih[orig] + bhh[orig];
}

__global__ __launch_bounds__(256) void pc_prep_k(const float* __restrict__ Wih1,
                                                 float* __restrict__ pc)
{
    int np = blockIdx.x * 256 + threadIdx.x;
    int orig = ((np & 3) << 9) | (np >> 2);
    pc[np] = Wih1[(size_t)orig * (NINP + 1) + NINP];
}

extern "C" void kernel_launch(void* const* d_in, const int* in_sizes, int n_in,
                              void* d_out, int out_size, void* d_ws, size_t ws_size,
                              hipStream_t stream)
{
    const float* input = (const float*)d_in[0];
    const float* Wih_p = (const float*)d_in[1];
    const float* Whh_p = (const float*)d_in[2];
    const float* bih_p = (const float*)d_in[3];
    const float* bhh_p = (const float*)d_in[4];
    const float* Wih1  = (const float*)d_in[5];
    const float* Whh1  = (const float*)d_in[6];
    const float* bih1  = (const float*)d_in[7];
    const float* bhh1  = (const float*)d_in[8];
    const float* Wih2  = (const float*)d_in[9];
    const float* Whh2  = (const float*)d_in[10];
    const float* bih2  = (const float*)d_in[11];
    const float* bhh2  = (const float*)d_in[12];
    const float* Wl    = (const float*)d_in[13];
    const float* bl    = (const float*)d_in[14];
    float* out = (float*)d_out;

    const size_t HC = (size_t)BATCH * NH;       // 1M elems
    char* p = (char*)d_ws;
    auto alloc = [&](size_t bytes) { char* r = p; p += (bytes + 255) & ~(size_t)255; return r; };

    // --- zeroed region first ---
    float* c_p = (float*)alloc(HC * 4);
    float* c1  = (float*)alloc(HC * 4);
    float* c2  = (float*)alloc(HC * 4);
    ushort* hps_hi[2]; ushort* hps_lo[2];
    ushort* h1s_hi[2]; ushort* h1s_lo[2];
    ushort* h2s_hi[2]; ushort* h2s_lo[2];
    for (int i = 0; i < 2; ++i) { hps_hi[i] = (ushort*)alloc(HC * 2); hps_lo[i] = (ushort*)alloc(HC * 2); }
    for (int i = 0; i < 2; ++i) { h1s_hi[i] = (ushort*)alloc(HC * 2); h1s_lo[i] = (ushort*)alloc(HC * 2); }
    for (int i = 0; i < 2; ++i) { h2s_hi[i] = (ushort*)alloc(HC * 2); h2s_lo[i] = (ushort*)alloc(HC * 2); }
    size_t zbytes = (size_t)(p - (char*)d_ws);

    // --- non-zeroed ---
    float* outs_p = (float*)alloc((size_t)T * BATCH * 4);
    float* pias   = (float*)alloc((size_t)T * BATCH * 4);
    ushort* WhhP_hi = (ushort*)alloc((size_t)G4 * NH * 2);
    ushort* WhhP_lo = (ushort*)alloc((size_t)G4 * NH * 2);
    ushort* WihP_hi = (ushort*)alloc((size_t)G4 * NINP * 2);
    ushort* WihP_lo = (ushort*)alloc((size_t)G4 * NINP * 2);
    ushort* Whh1_hi = (ushort*)alloc((size_t)G4 * NH * 2);
    ushort* Whh1_lo = (ushort*)alloc((size_t)G4 * NH * 2);
    ushort* Wih1x_hi = (ushort*)alloc((size_t)G4 * NINP * 2);
    ushort* Wih1x_lo = (ushort*)alloc((size_t)G4 * NINP * 2);
    ushort* Wih2_hi = (ushort*)alloc((size_t)G4 * NH * 2);
    ushort* Wih2_lo = (ushort*)alloc((size_t)G4 * NH * 2);
    ushort* Whh2_hi = (ushort*)alloc((size_t)G4 * NH * 2);
    ushort* Whh2_lo = (ushort*)alloc((size_t)G4 * NH * 2);
    float* biasP = (float*)alloc(G4 * 4);
    float* bias1 = (float*)alloc(G4 * 4);
    float* bias2 = (float*)alloc(G4 * 4);
    float* pc1   = (float*)alloc(G4 * 4);

    hipMemsetAsync(d_ws, 0, zbytes, stream);

    // weight prep
    split_perm_w_k<<<(G4 * NH) / 256, 256, 0, stream>>>(Whh_p, WhhP_hi, WhhP_lo, NH, 9);
    split_perm_w_k<<<(G4 * NINP) / 256, 256, 0, stream>>>(Wih_p, WihP_hi, WihP_lo, NINP, 6);
    split_perm_w_k<<<(G4 * NH) / 256, 256, 0, stream>>>(Whh1, Whh1_hi, Whh1_lo, NH, 9);
    split_perm_w_k<<<(G4 * NINP) / 256, 256, 0, stream>>>(Wih1, Wih1x_hi, Wih1x_lo, NINP + 1, 6);
    split_perm_w_k<<<(G4 * NH) / 256, 256, 0, stream>>>(Wih2, Wih2_hi, Wih2_lo, NH, 9);
    split_perm_w_k<<<(G4 * NH) / 256, 256, 0, stream>>>(Whh2, Whh2_hi, Whh2_lo, NH, 9);
    bias_prep_k<<<G4 / 256, 256, 0, stream>>>(bih_p, bhh_p, biasP);
    bias_prep_k<<<G4 / 256, 256, 0, stream>>>(bih1, bhh1, bias1);
    bias_prep_k<<<G4 / 256, 256, 0, stream>>>(bih2, bhh2, bias2);
    pc_prep_k<<<G4 / 256, 256, 0, stream>>>(Wih1, pc1);

    dim3 sgrid(G4 / 64, BATCH / 128);
    dim3 ogrid(BATCH / 4);

    // Phase 1
    for (int t = 0; t < T; ++t) {
        int rb = t & 1, wb = (t + 1) & 1;
        lstm_step_k<<<sgrid, 256, 0, stream>>>(
            hps_hi[rb], hps_lo[rb], NH, WhhP_hi, WhhP_lo, NH,
            nullptr, nullptr, 0, nullptr, nullptr, 0,
            input + (size_t)t * NINP, LDIN, WihP_hi, WihP_lo, NINP,
            biasP, nullptr, nullptr,
            c_p, hps_hi[wb], hps_lo[wb],
            (t > 0) ? hps_hi[rb] : nullptr, hps_lo[rb], Wl, bl,
            outs_p + (size_t)(t - 1) * BATCH, 1);
    }
    // out_proj for t = T-1 (h in hps[(T)&1] = hps[0])
    out_proj_hl<<<ogrid, 256, 0, stream>>>(hps_hi[T & 1], hps_lo[T & 1], Wl, bl,
                                           outs_p + (size_t)(T - 1) * BATCH, 1);

    pias_k<<<(T * BATCH) / 256, 256, 0, stream>>>(outs_p, input, pias, out);

    // Phase 2
    for (int t = 0; t < T; ++t) {
        int rb = t & 1, wb = (t + 1) & 1;
        lstm_step_k<<<sgrid, 256, 0, stream>>>(
            h1s_hi[rb], h1s_lo[rb], NH, Whh1_hi, Whh1_lo, NH,
            nullptr, nullptr, 0, nullptr, nullptr, 0,
            input + (size_t)t * NINP, LDIN, Wih1x_hi, Wih1x_lo, NINP,
            bias1, pias + (size_t)t * BATCH, pc1,
            c1, h1s_hi[wb], h1s_lo[wb],
            (t > 0) ? h2s_hi[rb] : nullptr, h2s_lo[rb], Wl, bl,
            out + (t - 1), T + 1);
        lstm_step_k<<<sgrid, 256, 0, stream>>>(
            h1s_hi[wb], h1s_lo[wb], NH, Wih2_hi, Wih2_lo, NH,
            h2s_hi[rb], h2s_lo[rb], NH, Whh2_hi, Whh2_lo, NH,
            nullptr, 0, nullptr, nullptr, 0,
            bias2, nullptr, nullptr,
            c2, h2s_hi[wb], h2s_lo[wb],
            nullptr, nullptr, nullptr, nullptr, nullptr, 0);
    }
    // out_proj for t = T-1 (h2 in h2s[T&1] = h2s[0])
    out_proj_hl<<<ogrid, 256, 0, stream>>>(h2s_hi[T & 1], h2s_lo[T & 1], Wl, bl,
                                           out + (T - 1), T + 1);
}

// Round 4
// 6099.413 us; speedup vs baseline: 4.6201x; 1.1579x over previous
//
#include <hip/hip_runtime.h>
#include <math.h>

#define NINP 64
#define NH 512
#define G4 2048   // 4*NH
#define T 64
#define BATCH 2048
#define LDIN 4097 // T*NINP+1

typedef __bf16 bf16x8 __attribute__((ext_vector_type(8)));
typedef float f32x4 __attribute__((ext_vector_type(4)));
typedef unsigned short ushort8 __attribute__((ext_vector_type(8)));

__device__ __forceinline__ float sigmf(float x) { return 1.0f / (1.0f + expf(-x)); }

__device__ __forceinline__ unsigned int bfhi_bits(float f) {
    unsigned int u = __float_as_uint(f);
    return (u + 0x7fffu + ((u >> 16) & 1u)) >> 16;
}
__device__ __forceinline__ float bf_to_f(unsigned int bits) {
    return __uint_as_float(bits << 16);
}

// ---------------------------------------------------------------------------
// Fused gates-GEMM (split-bf16 MFMA) + LSTM cell epilogue.
// Double-buffered K-pipeline with register prefetch (1 barrier / K-step).
// Gate columns PERMUTED: n' = j*4 + g. Tile: 128(b) x 64(n'), BK=32, 4 waves.
// XCD-pinned mapping: bid&7 selects a fixed group of 4 n-blocks, so each
// XCD's weight slice stays L2-resident across all 64 time steps.
// Optional prologue: out-projection of previous step's h (+ pia scaling).
// ---------------------------------------------------------------------------
__global__ __launch_bounds__(256) void lstm_step_k(
    const ushort* __restrict__ A0hi, const ushort* __restrict__ A0lo,
    const ushort* __restrict__ W0hi, const ushort* __restrict__ W0lo, int K0,
    const ushort* __restrict__ A1hi, const ushort* __restrict__ A1lo,
    const ushort* __restrict__ W1hi, const ushort* __restrict__ W1lo, int K1,
    const float*  __restrict__ Xf, int ldx,
    const ushort* __restrict__ Wxhi, const ushort* __restrict__ Wxlo, int Kx,
    const float* __restrict__ biasperm,
    const float* __restrict__ pv, const float* __restrict__ pcperm,
    float* __restrict__ c,
    ushort* __restrict__ hhi, ushort* __restrict__ hlo,
    const ushort* __restrict__ ophi, const ushort* __restrict__ oplo,
    const float* __restrict__ Wl, const float* __restrict__ blv,
    const float* __restrict__ scaleBase,   // input (stride LDIN), col LDIN-1
    float* __restrict__ piadst,            // |proj|*scale dest (or null)
    float* __restrict__ odst, int ostride) // raw proj dest (or null)
{
    // LDS: two staging buffers; f32 gate re-layout buffer aliases them.
    // Per buffer (ushorts): As_hi 128*40, As_lo 128*40, Ws_hi 64*40, Ws_lo 64*40
    __shared__ ushort smem[2 * 15360];            // 61440 B
    float (*Gs)[66] = (float(*)[66])smem;         // 33792 B, aliased

    const int tid = threadIdx.x;
    const int lane = tid & 63;
    const int wid = tid >> 6;
    const int bid = blockIdx.x;

    // XCD-pinned tile mapping: xcd = bid&7 owns n-blocks 4*xcd .. 4*xcd+3
    const int xcd = bid & 7;
    const int idx8 = bid >> 3;
    const int nblk = xcd * 4 + (idx8 & 3);
    const int mblk = idx8 >> 2;
    const int m0 = mblk * 128;
    const int n0 = nblk * 64;

    // ---- prologue: out-projection of previous h (no LDS, before pipeline) ----
    if (ophi != nullptr) {
        int row = bid * 4 + wid;
        ushort8 hh8 = *(const ushort8*)&ophi[(size_t)row * NH + lane * 8];
        ushort8 hl8 = *(const ushort8*)&oplo[(size_t)row * NH + lane * 8];
        const float4* wv = (const float4*)(Wl + lane * 8);
        float4 w0 = wv[0], w1 = wv[1];
        float wreg[8] = {w0.x, w0.y, w0.z, w0.w, w1.x, w1.y, w1.z, w1.w};
        float s = 0.f;
        #pragma unroll
        for (int e = 0; e < 8; ++e) {
            float h = bf_to_f(hh8[e]) + bf_to_f(hl8[e]);
            s = fmaf(h, wreg[e], s);
        }
        #pragma unroll
        for (int off = 32; off > 0; off >>= 1) s += __shfl_down(s, off);
        if (lane == 0) {
            float proj = s + blv[0];
            if (odst) odst[(size_t)row * ostride] = proj;
            if (piadst) piadst[row] = fabsf(proj) * scaleBase[(size_t)row * LDIN + (LDIN - 1)];
        }
    }

    const int wm = wid >> 1;
    const int wn = wid & 1;
    const int fr = lane & 15;
    const int fg = lane >> 4;
    const int srow = tid >> 2;          // 0..63
    const int scol = (tid & 3) * 8;     // 0,8,16,24

    const int ntx = Kx >> 5;            // X tiles first
    const int nt0 = K0 >> 5;
    const int nt1 = K1 >> 5;
    const int NT = ntx + nt0 + nt1;

    // staged registers (prefetch set)
    ushort8 sa0h, sa0l, sa1h, sa1l, swh, swl;
    float4 sx00, sx01, sx10, sx11;

    auto issue = [&](int t) {
        if (t < ntx) {
            int kt = t * 32;
            const float* src0 = Xf + (size_t)(m0 + srow) * ldx + kt + scol;
            const float* src1 = Xf + (size_t)(m0 + srow + 64) * ldx + kt + scol;
            sx00 = *(const float4*)src0;  sx01 = *(const float4*)(src0 + 4);
            sx10 = *(const float4*)src1;  sx11 = *(const float4*)(src1 + 4);
            swh = *(const ushort8*)&Wxhi[(size_t)(n0 + srow) * Kx + kt + scol];
            swl = *(const ushort8*)&Wxlo[(size_t)(n0 + srow) * Kx + kt + scol];
        } else if (t < ntx + nt0) {
            int kt = (t - ntx) * 32;
            sa0h = *(const ushort8*)&A0hi[(size_t)(m0 + srow) * NH + kt + scol];
            sa0l = *(const ushort8*)&A0lo[(size_t)(m0 + srow) * NH + kt + scol];
            sa1h = *(const ushort8*)&A0hi[(size_t)(m0 + srow + 64) * NH + kt + scol];
            sa1l = *(const ushort8*)&A0lo[(size_t)(m0 + srow + 64) * NH + kt + scol];
            swh = *(const ushort8*)&W0hi[(size_t)(n0 + srow) * K0 + kt + scol];
            swl = *(const ushort8*)&W0lo[(size_t)(n0 + srow) * K0 + kt + scol];
        } else {
            int kt = (t - ntx - nt0) * 32;
            sa0h = *(const ushort8*)&A1hi[(size_t)(m0 + srow) * NH + kt + scol];
            sa0l = *(const ushort8*)&A1lo[(size_t)(m0 + srow) * NH + kt + scol];
            sa1h = *(const ushort8*)&A1hi[(size_t)(m0 + srow + 64) * NH + kt + scol];
            sa1l = *(const ushort8*)&A1lo[(size_t)(m0 + srow + 64) * NH + kt + scol];
            swh = *(const ushort8*)&W1hi[(size_t)(n0 + srow) * K1 + kt + scol];
            swl = *(const ushort8*)&W1lo[(size_t)(n0 + srow) * K1 + kt + scol];
        }
    };

    auto dswr = [&](int t, int buf) {
        ushort* bp = smem + buf * 15360;
        ushort (*As_hi)[40] = (ushort(*)[40])bp;
        ushort (*As_lo)[40] = (ushort(*)[40])(bp + 5120);
        ushort (*Ws_hi)[40] = (ushort(*)[40])(bp + 10240);
        ushort (*Ws_lo)[40] = (ushort(*)[40])(bp + 12800);
        if (t < ntx) {
            float xv0[8] = {sx00.x, sx00.y, sx00.z, sx00.w, sx01.x, sx01.y, sx01.z, sx01.w};
            float xv1[8] = {sx10.x, sx10.y, sx10.z, sx10.w, sx11.x, sx11.y, sx11.z, sx11.w};
            ushort8 h0, l0, h1, l1;
            #pragma unroll
            for (int e = 0; e < 8; ++e) {
                unsigned int hb0 = bfhi_bits(xv0[e]);
                h0[e] = (unsigned short)hb0;
                l0[e] = (unsigned short)bfhi_bits(xv0[e] - bf_to_f(hb0));
                unsigned int hb1 = bfhi_bits(xv1[e]);
                h1[e] = (unsigned short)hb1;
                l1[e] = (unsigned short)bfhi_bits(xv1[e] - bf_to_f(hb1));
            }
            *(ushort8*)&As_hi[srow][scol] = h0;
            *(ushort8*)&As_lo[srow][scol] = l0;
            *(ushort8*)&As_hi[srow + 64][scol] = h1;
            *(ushort8*)&As_lo[srow + 64][scol] = l1;
        } else {
            *(ushort8*)&As_hi[srow][scol] = sa0h;
            *(ushort8*)&As_lo[srow][scol] = sa0l;
            *(ushort8*)&As_hi[srow + 64][scol] = sa1h;
            *(ushort8*)&As_lo[srow + 64][scol] = sa1l;
        }
        *(ushort8*)&Ws_hi[srow][scol] = swh;
        *(ushort8*)&Ws_lo[srow][scol] = swl;
    };

    f32x4 acc[4][2] = {};
    int cur = 0;

    issue(0);
    dswr(0, 0);

    for (int t = 0; t < NT; ++t) {
        if (t + 1 < NT) issue(t + 1);          // prefetch next tile's globals
        __syncthreads();                        // buf[cur] ready for all waves

        const ushort* bp = smem + cur * 15360;
        const ushort (*As_hi)[40] = (const ushort(*)[40])bp;
        const ushort (*As_lo)[40] = (const ushort(*)[40])(bp + 5120);
        const ushort (*Ws_hi)[40] = (const ushort(*)[40])(bp + 10240);
        const ushort (*Ws_lo)[40] = (const ushort(*)[40])(bp + 12800);

        bf16x8 ah[4], al[4], wh[2], wl[2];
        #pragma unroll
        for (int im = 0; im < 4; ++im)
            ah[im] = *(const bf16x8*)&As_hi[wm * 64 + im * 16 + fr][fg * 8];
        #pragma unroll
        for (int in = 0; in < 2; ++in)
            wh[in] = *(const bf16x8*)&Ws_hi[wn * 32 + in * 16 + fr][fg * 8];
        #pragma unroll
        for (int im = 0; im < 4; ++im)
            #pragma unroll
            for (int in = 0; in < 2; ++in)
                acc[im][in] = __builtin_amdgcn_mfma_f32_16x16x32_bf16(ah[im], wh[in], acc[im][in], 0, 0, 0);
        #pragma unroll
        for (int in = 0; in < 2; ++in)
            wl[in] = *(const bf16x8*)&Ws_lo[wn * 32 + in * 16 + fr][fg * 8];
        #pragma unroll
        for (int im = 0; im < 4; ++im)
            #pragma unroll
            for (int in = 0; in < 2; ++in)
                acc[im][in] = __builtin_amdgcn_mfma_f32_16x16x32_bf16(ah[im], wl[in], acc[im][in], 0, 0, 0);
        #pragma unroll
        for (int im = 0; im < 4; ++im)
            al[im] = *(const bf16x8*)&As_lo[wm * 64 + im * 16 + fr][fg * 8];
        #pragma unroll
        for (int im = 0; im < 4; ++im)
            #pragma unroll
            for (int in = 0; in < 2; ++in)
                acc[im][in] = __builtin_amdgcn_mfma_f32_16x16x32_bf16(al[im], wh[in], acc[im][in], 0, 0, 0);

        if (t + 1 < NT) dswr(t + 1, cur ^ 1);  // vmcnt wait lands here, after MFMA
        cur ^= 1;
    }

    // ---- epilogue stage 1: bias + pia, dump fragments to LDS (f32) ----
    __syncthreads();   // all waves done reading staging buffers (aliased w/ Gs)
    #pragma unroll
    for (int im = 0; im < 4; ++im) {
        int rowl = wm * 64 + im * 16 + fg * 4;
        #pragma unroll
        for (int in = 0; in < 2; ++in) {
            int npl = wn * 32 + in * 16 + fr;
            int np = n0 + npl;
            float bias = biasperm[np];
            float pcv = (pcperm != nullptr) ? pcperm[np] : 0.0f;
            #pragma unroll
            for (int r = 0; r < 4; ++r) {
                float g = acc[im][in][r] + bias;
                if (pv != nullptr) g += pv[m0 + rowl + r] * pcv;
                Gs[rowl + r][npl] = g;
            }
        }
    }
    __syncthreads();

    // ---- epilogue stage 2: per-cell update, fully coalesced I/O ----
    {
        int bloc = tid >> 1;
        int j8 = (tid & 1) * 8;
        int bglob = m0 + bloc;
        int jbase = (n0 >> 2) + j8;
        size_t idx = (size_t)bglob * NH + jbase;
        float4 cold0 = *(const float4*)&c[idx];
        float4 cold1 = *(const float4*)&c[idx + 4];
        float cold[8] = {cold0.x, cold0.y, cold0.z, cold0.w,
                         cold1.x, cold1.y, cold1.z, cold1.w};
        float cn[8], hn[8];
        #pragma unroll
        for (int jj = 0; jj < 8; ++jj) {
            int col = (j8 + jj) * 4;
            float2 gab = *(const float2*)&Gs[bloc][col];
            float2 gcd = *(const float2*)&Gs[bloc][col + 2];
            float cnv = sigmf(gab.y) * cold[jj] + sigmf(gab.x) * tanhf(gcd.x);
            cn[jj] = cnv;
            hn[jj] = sigmf(gcd.y) * tanhf(cnv);
        }
        float4 cs0 = {cn[0], cn[1], cn[2], cn[3]};
        float4 cs1 = {cn[4], cn[5], cn[6], cn[7]};
        *(float4*)&c[idx] = cs0;
        *(float4*)&c[idx + 4] = cs1;
        ushort8 hh, hl;
        #pragma unroll
        for (int jj = 0; jj < 8; ++jj) {
            unsigned int hb = bfhi_bits(hn[jj]);
            hh[jj] = (unsigned short)hb;
            hl[jj] = (unsigned short)bfhi_bits(hn[jj] - bf_to_f(hb));
        }
        *(ushort8*)&hhi[idx] = hh;
        *(ushort8*)&hlo[idx] = hl;
    }
}

// Standalone out-projection from hi/lo split h (tail steps), with optional pia.
__global__ __launch_bounds__(256) void out_proj_hl(const ushort* __restrict__ hhi,
                                                   const ushort* __restrict__ hlo,
                                                   const float* __restrict__ Wl,
                                                   const float* __restrict__ blv,
                                                   const float* __restrict__ scaleBase,
                                                   float* __restrict__ piadst,
                                                   float* __restrict__ odst, int ostride)
{
    int wave = threadIdx.x >> 6;
    int lane = threadIdx.x & 63;
    int row = blockIdx.x * 4 + wave;
    ushort8 hh8 = *(const ushort8*)&hhi[(size_t)row * NH + lane * 8];
    ushort8 hl8 = *(const ushort8*)&hlo[(size_t)row * NH + lane * 8];
    const float4* wv = (const float4*)(Wl + lane * 8);
    float4 w0 = wv[0], w1 = wv[1];
    float wreg[8] = {w0.x, w0.y, w0.z, w0.w, w1.x, w1.y, w1.z, w1.w};
    float s = 0.f;
    #pragma unroll
    for (int e = 0; e < 8; ++e) {
        float h = bf_to_f(hh8[e]) + bf_to_f(hl8[e]);
        s = fmaf(h, wreg[e], s);
    }
    #pragma unroll
    for (int off = 32; off > 0; off >>= 1) s += __shfl_down(s, off);
    if (lane == 0) {
        float proj = s + blv[0];
        if (odst) odst[(size_t)row * ostride] = proj;
        if (piadst) piadst[row] = fabsf(proj) * scaleBase[(size_t)row * LDIN + (LDIN - 1)];
    }
}

// Split W[4NH][ldw] (cols 0..K-1) into permuted bf16 hi/lo, n' = j*4+g.
__global__ __launch_bounds__(256) void split_perm_w_k(const float* __restrict__ W,
                                                      ushort* __restrict__ whi,
                                                      ushort* __restrict__ wlo,
                                                      int ldw, int kshift)
{
    int idx = blockIdx.x * 256 + threadIdx.x;
    int K = 1 << kshift;
    int np = idx >> kshift;
    int k = idx & (K - 1);
    int orig = ((np & 3) << 9) | (np >> 2);
    float v = W[(size_t)orig * ldw + k];
    unsigned int hb = bfhi_bits(v);
    whi[idx] = (unsigned short)hb;
    wlo[idx] = (unsigned short)bfhi_bits(v - bf_to_f(hb));
}

__global__ __launch_bounds__(256) void bias_prep_k(const float* __restrict__ bih,
                                                   const float* __restrict__ bhh,
                                                   float* __restrict__ bperm)
{
    int np = blockIdx.x * 256 + threadIdx.x;
    int orig = ((np & 3) << 9) | (np >> 2);
    bperm[np] = bih[orig] + bhh[orig];
}

__global__ __launch_bounds__(256) void pc_prep_k(const float* __restrict__ Wih1,
                                                 float* __restrict__ pc)
{
    int np = blockIdx.x * 256 + threadIdx.x;
    int orig = ((np & 3) << 9) | (np >> 2);
    pc[np] = Wih1[(size_t)orig * (NINP + 1) + NINP];
}

extern "C" void kernel_launch(void* const* d_in, const int* in_sizes, int n_in,
                              void* d_out, int out_size, void* d_ws, size_t ws_size,
                              hipStream_t stream)
{
    const float* input = (const float*)d_in[0];
    const float* Wih_p = (const float*)d_in[1];
    const float* Whh_p = (const float*)d_in[2];
    const float* bih_p = (const float*)d_in[3];
    const float* bhh_p = (const float*)d_in[4];
    const float* Wih1  = (const float*)d_in[5];
    const float* Whh1  = (const float*)d_in[6];
    const float* bih1  = (const float*)d_in[7];
    const float* bhh1  = (const float*)d_in[8];
    const float* Wih2  = (const float*)d_in[9];
    const float* Whh2  = (const float*)d_in[10];
    const float* bih2  = (const float*)d_in[11];
    const float* bhh2  = (const float*)d_in[12];
    const float* Wl    = (const float*)d_in[13];
    const float* bl    = (const float*)d_in[14];
    float* out = (float*)d_out;

    const size_t HC = (size_t)BATCH * NH;       // 1M elems
    char* p = (char*)d_ws;
    auto alloc = [&](size_t bytes) { char* r = p; p += (bytes + 255) & ~(size_t)255; return r; };

    // --- zeroed region first ---
    float* c_p = (float*)alloc(HC * 4);
    float* c1  = (float*)alloc(HC * 4);
    float* c2  = (float*)alloc(HC * 4);
    ushort* hps_hi[2]; ushort* hps_lo[2];
    ushort* h1s_hi[2]; ushort* h1s_lo[2];
    ushort* h2s_hi[2]; ushort* h2s_lo[2];
    for (int i = 0; i < 2; ++i) { hps_hi[i] = (ushort*)alloc(HC * 2); hps_lo[i] = (ushort*)alloc(HC * 2); }
    for (int i = 0; i < 2; ++i) { h1s_hi[i] = (ushort*)alloc(HC * 2); h1s_lo[i] = (ushort*)alloc(HC * 2); }
    for (int i = 0; i < 2; ++i) { h2s_hi[i] = (ushort*)alloc(HC * 2); h2s_lo[i] = (ushort*)alloc(HC * 2); }
    size_t zbytes = (size_t)(p - (char*)d_ws);

    // --- non-zeroed ---
    float* pias   = (float*)alloc((size_t)T * BATCH * 4);
    ushort* WhhP_hi = (ushort*)alloc((size_t)G4 * NH * 2);
    ushort* WhhP_lo = (ushort*)alloc((size_t)G4 * NH * 2);
    ushort* WihP_hi = (ushort*)alloc((size_t)G4 * NINP * 2);
    ushort* WihP_lo = (ushort*)alloc((size_t)G4 * NINP * 2);
    ushort* Whh1_hi = (ushort*)alloc((size_t)G4 * NH * 2);
    ushort* Whh1_lo = (ushort*)alloc((size_t)G4 * NH * 2);
    ushort* Wih1x_hi = (ushort*)alloc((size_t)G4 * NINP * 2);
    ushort* Wih1x_lo = (ushort*)alloc((size_t)G4 * NINP * 2);
    ushort* Wih2_hi = (ushort*)alloc((size_t)G4 * NH * 2);
    ushort* Wih2_lo = (ushort*)alloc((size_t)G4 * NH * 2);
    ushort* Whh2_hi = (ushort*)alloc((size_t)G4 * NH * 2);
    ushort* Whh2_lo = (ushort*)alloc((size_t)G4 * NH * 2);
    float* biasP = (float*)alloc(G4 * 4);
    float* bias1 = (float*)alloc(G4 * 4);
    float* bias2 = (float*)alloc(G4 * 4);
    float* pc1   = (float*)alloc(G4 * 4);

    hipMemsetAsync(d_ws, 0, zbytes, stream);

    // weight prep
    split_perm_w_k<<<(G4 * NH) / 256, 256, 0, stream>>>(Whh_p, WhhP_hi, WhhP_lo, NH, 9);
    split_perm_w_k<<<(G4 * NINP) / 256, 256, 0, stream>>>(Wih_p, WihP_hi, WihP_lo, NINP, 6);
    split_perm_w_k<<<(G4 * NH) / 256, 256, 0, stream>>>(Whh1, Whh1_hi, Whh1_lo, NH, 9);
    split_perm_w_k<<<(G4 * NINP) / 256, 256, 0, stream>>>(Wih1, Wih1x_hi, Wih1x_lo, NINP + 1, 6);
    split_perm_w_k<<<(G4 * NH) / 256, 256, 0, stream>>>(Wih2, Wih2_hi, Wih2_lo, NH, 9);
    split_perm_w_k<<<(G4 * NH) / 256, 256, 0, stream>>>(Whh2, Whh2_hi, Whh2_lo, NH, 9);
    bias_prep_k<<<G4 / 256, 256, 0, stream>>>(bih_p, bhh_p, biasP);
    bias_prep_k<<<G4 / 256, 256, 0, stream>>>(bih1, bhh1, bias1);
    bias_prep_k<<<G4 / 256, 256, 0, stream>>>(bih2, bhh2, bias2);
    pc_prep_k<<<G4 / 256, 256, 0, stream>>>(Wih1, pc1);

    dim3 sgrid(512);
    dim3 ogrid(BATCH / 4);

    // Phase 1
    for (int t = 0; t < T; ++t) {
        int rb = t & 1, wb = (t + 1) & 1;
        lstm_step_k<<<sgrid, 256, 0, stream>>>(
            hps_hi[rb], hps_lo[rb], WhhP_hi, WhhP_lo, NH,
            nullptr, nullptr, nullptr, nullptr, 0,
            input + (size_t)t * NINP, LDIN, WihP_hi, WihP_lo, NINP,
            biasP, nullptr, nullptr,
            c_p, hps_hi[wb], hps_lo[wb],
            (t > 0) ? hps_hi[rb] : nullptr, hps_lo[rb], Wl, bl,
            input, (t > 0) ? pias + (size_t)(t - 1) * BATCH : nullptr,
            nullptr, 0);
    }
    // tail: proj of h_p(T-1) -> out[:,T] (raw) and pias[T-1] (scaled)
    out_proj_hl<<<ogrid, 256, 0, stream>>>(hps_hi[T & 1], hps_lo[T & 1], Wl, bl,
                                           input, pias + (size_t)(T - 1) * BATCH,
                                           out + T, T + 1);

    // Phase 2
    for (int t = 0; t < T; ++t) {
        int rb = t & 1, wb = (t + 1) & 1;
        lstm_step_k<<<sgrid, 256, 0, stream>>>(
            h1s_hi[rb], h1s_lo[rb], Whh1_hi, Whh1_lo, NH,
            nullptr, nullptr, nullptr, nullptr, 0,
            input + (size_t)t * NINP, LDIN, Wih1x_hi, Wih1x_lo, NINP,
            bias1, pias + (size_t)t * BATCH, pc1,
            c1, h1s_hi[wb], h1s_lo[wb],
            (t > 0) ? h2s_hi[rb] : nullptr, h2s_lo[rb], Wl, bl,
            input, nullptr,
            (t > 0) ? out + (t - 1) : nullptr, T + 1);
        lstm_step_k<<<sgrid, 256, 0, stream>>>(
            h1s_hi[wb], h1s_lo[wb], Wih2_hi, Wih2_lo, NH,
            h2s_hi[rb], h2s_lo[rb], Whh2_hi, Whh2_lo, NH,
            nullptr, 0, nullptr, nullptr, 0,
            bias2, nullptr, nullptr,
            c2, h2s_hi[wb], h2s_lo[wb],
            nullptr, nullptr, nullptr, nullptr,
            nullptr, nullptr, nullptr, 0);
    }
    // tail: proj of h2(T-1) -> out[:,T-1]
    out_proj_hl<<<ogrid, 256, 0, stream>>>(h2s_hi[T & 1], h2s_lo[T & 1], Wl, bl,
                                           input, nullptr,
                                           out + (T - 1), T + 1);
}